// Round 9
// baseline (488.696 us; speedup 1.0000x reference)
//
#include <hip/hip_runtime.h>

// PeriodicDistance: fused gather + PBC-shift + norm + passthrough kernel.
//
// Inputs: pos[N,3] f32, box[1,3,3] f32, edge_index[2,E] i32,
//         shifts_idx[E,3] i32, batch_map[E] i32.
// Output (flat f32): edge_index (2E) | edge_weight (E) | edge_vec (3E) |
//   shifts_idx (3E)  — int outputs stored as converted floats.
//
// Ladder: R4 baseline 143us (traffic ideal: FETCH 98.5/WRITE 229.8 MB, but
// 2.3 TB/s, VALUBusy 5.6% -> gather-latency bound). R5 dwordx3 gathers:
// neutral (compiler already merged). R8 nontemporal streams: ~123us (-14%,
// L2 thrash was real but partial). R9: 8 edges/thread -> 16 independent
// position gathers in flight per thread (2x MLP), gathers issued FIRST.

typedef int   vint4   __attribute__((ext_vector_type(4)));
typedef float vfloat4 __attribute__((ext_vector_type(4)));

struct f3 { float x, y, z; };   // 12 B gather (global_load_dwordx3)

template <bool MULTI>
__global__ __launch_bounds__(256) void pd_kernel(
    const float* __restrict__ pos,
    const float* __restrict__ box,   // [n_struct,3,3] row-major
    const int*   __restrict__ ei,    // [2,E]
    const int*   __restrict__ sh,    // [E,3]
    const int*   __restrict__ bmap,  // [E]
    float* __restrict__ out,
    const long long E)
{
    const long long nG = E >> 3;                 // full groups of 8 edges
    float* out_ei = out;                 // 2E floats (converted ints)
    float* out_w  = out + 2 * E;         // E floats
    float* out_v  = out + 3 * E;         // 3E floats
    float* out_s  = out + 6 * E;         // 3E floats (converted ints)

    // Single-structure fast path: box in registers (uniform scalar loads).
    float b00, b01, b02, b10, b11, b12, b20, b21, b22;
    if (!MULTI) {
        b00 = box[0]; b01 = box[1]; b02 = box[2];
        b10 = box[3]; b11 = box[4]; b12 = box[5];
        b20 = box[6]; b21 = box[7]; b22 = box[8];
    }

    const long long stride = (long long)gridDim.x * blockDim.x;

    for (long long g = (long long)blockIdx.x * blockDim.x + threadIdx.x;
         g < nG; g += stride) {
        const long long e0 = g << 3;

        // 1) Edge indices first (gather addresses depend on them).
        const vint4 iA = __builtin_nontemporal_load(
            reinterpret_cast<const vint4*>(ei + e0));
        const vint4 iB = __builtin_nontemporal_load(
            reinterpret_cast<const vint4*>(ei + e0 + 4));
        const vint4 jA = __builtin_nontemporal_load(
            reinterpret_cast<const vint4*>(ei + E + e0));
        const vint4 jB = __builtin_nontemporal_load(
            reinterpret_cast<const vint4*>(ei + E + e0 + 4));

        const int iv[8] = {iA.x, iA.y, iA.z, iA.w, iB.x, iB.y, iB.z, iB.w};
        const int jv[8] = {jA.x, jA.y, jA.z, jA.w, jB.x, jB.y, jB.z, jB.w};

        // 2) Issue all 16 position gathers immediately (longest latency).
        f3 piv[8], pjv[8];
#pragma unroll
        for (int k = 0; k < 8; ++k) {
            piv[k] = *reinterpret_cast<const f3*>(pos + 3LL * iv[k]);
            pjv[k] = *reinterpret_cast<const f3*>(pos + 3LL * jv[k]);
        }

        // 3) Shift rows (streaming, nontemporal).
        vint4 sv4[6];
#pragma unroll
        for (int t = 0; t < 6; ++t)
            sv4[t] = __builtin_nontemporal_load(
                reinterpret_cast<const vint4*>(sh + 3 * e0 + 4 * t));

        int bv[8] = {0, 0, 0, 0, 0, 0, 0, 0};
        if (MULTI) {
            const vint4 bA = __builtin_nontemporal_load(
                reinterpret_cast<const vint4*>(bmap + e0));
            const vint4 bB = __builtin_nontemporal_load(
                reinterpret_cast<const vint4*>(bmap + e0 + 4));
            bv[0] = bA.x; bv[1] = bA.y; bv[2] = bA.z; bv[3] = bA.w;
            bv[4] = bB.x; bv[5] = bB.y; bv[6] = bB.z; bv[7] = bB.w;
        }

        // 4) Pass-through stores (int -> float), nontemporal.
        __builtin_nontemporal_store(
            (vfloat4){(float)iA.x, (float)iA.y, (float)iA.z, (float)iA.w},
            reinterpret_cast<vfloat4*>(out_ei + e0));
        __builtin_nontemporal_store(
            (vfloat4){(float)iB.x, (float)iB.y, (float)iB.z, (float)iB.w},
            reinterpret_cast<vfloat4*>(out_ei + e0 + 4));
        __builtin_nontemporal_store(
            (vfloat4){(float)jA.x, (float)jA.y, (float)jA.z, (float)jA.w},
            reinterpret_cast<vfloat4*>(out_ei + E + e0));
        __builtin_nontemporal_store(
            (vfloat4){(float)jB.x, (float)jB.y, (float)jB.z, (float)jB.w},
            reinterpret_cast<vfloat4*>(out_ei + E + e0 + 4));
#pragma unroll
        for (int t = 0; t < 6; ++t) {
            __builtin_nontemporal_store(
                (vfloat4){(float)sv4[t].x, (float)sv4[t].y,
                          (float)sv4[t].z, (float)sv4[t].w},
                reinterpret_cast<vfloat4*>(out_s + 3 * e0 + 4 * t));
        }

        const int sv[24] = {sv4[0].x, sv4[0].y, sv4[0].z, sv4[0].w,
                            sv4[1].x, sv4[1].y, sv4[1].z, sv4[1].w,
                            sv4[2].x, sv4[2].y, sv4[2].z, sv4[2].w,
                            sv4[3].x, sv4[3].y, sv4[3].z, sv4[3].w,
                            sv4[4].x, sv4[4].y, sv4[4].z, sv4[4].w,
                            sv4[5].x, sv4[5].y, sv4[5].z, sv4[5].w};

        // 5) Math + result stores.
        float w[8], v[24];
#pragma unroll
        for (int k = 0; k < 8; ++k) {
            float B00, B01, B02, B10, B11, B12, B20, B21, B22;
            if (MULTI) {
                const float* bb = box + 9LL * bv[k];
                B00 = bb[0]; B01 = bb[1]; B02 = bb[2];
                B10 = bb[3]; B11 = bb[4]; B12 = bb[5];
                B20 = bb[6]; B21 = bb[7]; B22 = bb[8];
            } else {
                B00 = b00; B01 = b01; B02 = b02;
                B10 = b10; B11 = b11; B12 = b12;
                B20 = b20; B21 = b21; B22 = b22;
            }
            const float sx = (float)sv[3 * k + 0];
            const float sy = (float)sv[3 * k + 1];
            const float sz = (float)sv[3 * k + 2];
            // einsum 'en,enm->em': c[m] = sum_n s[n] * box[n][m]
            const float cx = sx * B00 + sy * B10 + sz * B20;
            const float cy = sx * B01 + sy * B11 + sz * B21;
            const float cz = sx * B02 + sy * B12 + sz * B22;

            const float dx = pjv[k].x - piv[k].x + cx;
            const float dy = pjv[k].y - piv[k].y + cy;
            const float dz = pjv[k].z - piv[k].z + cz;

            w[k] = sqrtf(dx * dx + dy * dy + dz * dz);
            v[3 * k + 0] = -dx;
            v[3 * k + 1] = -dy;
            v[3 * k + 2] = -dz;
        }

        __builtin_nontemporal_store(
            (vfloat4){w[0], w[1], w[2], w[3]},
            reinterpret_cast<vfloat4*>(out_w + e0));
        __builtin_nontemporal_store(
            (vfloat4){w[4], w[5], w[6], w[7]},
            reinterpret_cast<vfloat4*>(out_w + e0 + 4));
#pragma unroll
        for (int t = 0; t < 6; ++t) {
            __builtin_nontemporal_store(
                (vfloat4){v[4 * t + 0], v[4 * t + 1],
                          v[4 * t + 2], v[4 * t + 3]},
                reinterpret_cast<vfloat4*>(out_v + 3 * e0 + 4 * t));
        }
    }

    // Tail: E % 8 edges, scalar path (empty for E = 6.4M; kept for generality).
    const long long tail0 = nG << 3;
    for (long long e = tail0 + (long long)blockIdx.x * blockDim.x + threadIdx.x;
         e < E; e += stride) {
        const int i = ei[e];
        const int j = ei[E + e];
        const int s0 = sh[3 * e], s1 = sh[3 * e + 1], s2 = sh[3 * e + 2];
        out_ei[e]     = (float)i;
        out_ei[E + e] = (float)j;
        out_s[3 * e]     = (float)s0;
        out_s[3 * e + 1] = (float)s1;
        out_s[3 * e + 2] = (float)s2;

        float B00, B01, B02, B10, B11, B12, B20, B21, B22;
        if (MULTI) {
            const float* bb = box + 9LL * bmap[e];
            B00 = bb[0]; B01 = bb[1]; B02 = bb[2];
            B10 = bb[3]; B11 = bb[4]; B12 = bb[5];
            B20 = bb[6]; B21 = bb[7]; B22 = bb[8];
        } else {
            B00 = box[0]; B01 = box[1]; B02 = box[2];
            B10 = box[3]; B11 = box[4]; B12 = box[5];
            B20 = box[6]; B21 = box[7]; B22 = box[8];
        }
        const float sx = (float)s0, sy = (float)s1, sz = (float)s2;
        const float cx = sx * B00 + sy * B10 + sz * B20;
        const float cy = sx * B01 + sy * B11 + sz * B21;
        const float cz = sx * B02 + sy * B12 + sz * B22;
        const float dx = pos[3LL * j + 0] - pos[3LL * i + 0] + cx;
        const float dy = pos[3LL * j + 1] - pos[3LL * i + 1] + cy;
        const float dz = pos[3LL * j + 2] - pos[3LL * i + 2] + cz;
        out_w[e] = sqrtf(dx * dx + dy * dy + dz * dz);
        out_v[3 * e + 0] = -dx;
        out_v[3 * e + 1] = -dy;
        out_v[3 * e + 2] = -dz;
    }
}

extern "C" void kernel_launch(void* const* d_in, const int* in_sizes, int n_in,
                              void* d_out, int out_size, void* d_ws, size_t ws_size,
                              hipStream_t stream) {
    const float* pos  = (const float*)d_in[0];
    const float* box  = (const float*)d_in[1];
    const int*   ei   = (const int*)d_in[2];
    const int*   sh   = (const int*)d_in[3];
    const int*   bmap = (const int*)d_in[4];
    float* out = (float*)d_out;

    const long long E = (long long)in_sizes[4];     // batch_map length
    const int n_struct = in_sizes[1] / 9;

    const int block = 256;
    long long nG = (E + 7) >> 3;
    long long blocks = (nG + block - 1) / block;
    if (blocks < 1) blocks = 1;
    if (blocks > 65535) blocks = 65535;

    if (n_struct == 1) {
        pd_kernel<false><<<(int)blocks, block, 0, stream>>>(
            pos, box, ei, sh, bmap, out, E);
    } else {
        pd_kernel<true><<<(int)blocks, block, 0, stream>>>(
            pos, box, ei, sh, bmap, out, E);
    }
}

// Round 10
// 371.856 us; speedup vs baseline: 1.3142x; 1.3142x over previous
//
#include <hip/hip_runtime.h>

// PeriodicDistance: fused gather + PBC-shift + norm + passthrough kernel.
//
// Ladder:
//  R4  143us: traffic ideal (FETCH 98.5 / WRITE 229.8 MB) but 2.3 TB/s,
//      VALUBusy 5.6% -> gather-latency bound.
//  R5  neutral: dwordx3 gathers (compiler already merged scalars).
//  R8  ~123us: nontemporal streams -> pos stays in L2 (partial win).
//  R9  229us REGRESSION: 8 edges/thread -> 96B-stride NT stores broke L2
//      write-combining: WRITE_SIZE 230->409 MB. Lesson: NT stores MUST be
//      lane-contiguous.
//  R10: 4 edges/thread; NT loads kept; out_v/out_s routed through a 12KB
//      LDS transpose so ALL stores are lane-contiguous (16B/lane) NT stores.
//      Predict WRITE back to ~230MB, dur 80-105us.

typedef int   vint4   __attribute__((ext_vector_type(4)));
typedef float vfloat4 __attribute__((ext_vector_type(4)));

struct f3 { float x, y, z; };   // 12 B gather (global_load_dwordx3)

#define BLOCK 256
#define EPT   4                     // edges per thread
#define EPB   (BLOCK * EPT)         // 1024 edges per block

template <bool MULTI>
__global__ __launch_bounds__(BLOCK) void pd_kernel(
    const float* __restrict__ pos,
    const float* __restrict__ box,   // [n_struct,3,3] row-major
    const int*   __restrict__ ei,    // [2,E]
    const int*   __restrict__ sh,    // [E,3]
    const int*   __restrict__ bmap,  // [E]
    float* __restrict__ out,
    const long long E)
{
    __shared__ float lds[EPB * 3];   // 12 KB transpose staging (reused twice)

    float* out_ei = out;             // 2E floats (converted ints)
    float* out_w  = out + 2 * E;     // E floats
    float* out_v  = out + 3 * E;     // 3E floats
    float* out_s  = out + 6 * E;     // 3E floats (converted ints)

    const int tid = threadIdx.x;
    const long long E0 = (long long)blockIdx.x * EPB;

    float b00, b01, b02, b10, b11, b12, b20, b21, b22;
    if (!MULTI) {
        b00 = box[0]; b01 = box[1]; b02 = box[2];
        b10 = box[3]; b11 = box[4]; b12 = box[5];
        b20 = box[6]; b21 = box[7]; b22 = box[8];
    }

    if (E0 + EPB <= E) {
        // ---------- full-block fast path ----------
        const long long e0 = E0 + (long long)tid * EPT;

        // 1) Edge indices (NT, contiguous 16B/lane).
        const vint4 i4 = __builtin_nontemporal_load(
            reinterpret_cast<const vint4*>(ei + e0));
        const vint4 j4 = __builtin_nontemporal_load(
            reinterpret_cast<const vint4*>(ei + E + e0));
        const int iv[4] = {i4.x, i4.y, i4.z, i4.w};
        const int jv[4] = {j4.x, j4.y, j4.z, j4.w};

        // 2) Position gathers ASAP (longest latency; normal loads -> L2).
        f3 piv[4], pjv[4];
#pragma unroll
        for (int k = 0; k < 4; ++k) {
            piv[k] = *reinterpret_cast<const f3*>(pos + 3LL * iv[k]);
            pjv[k] = *reinterpret_cast<const f3*>(pos + 3LL * jv[k]);
        }

        // 3) Shift rows (NT; lane stride 48B on the load side is fine —
        //    all bytes of each line are consumed by neighboring lanes).
        const vint4 sA = __builtin_nontemporal_load(
            reinterpret_cast<const vint4*>(sh + 3 * e0));
        const vint4 sB = __builtin_nontemporal_load(
            reinterpret_cast<const vint4*>(sh + 3 * e0 + 4));
        const vint4 sC = __builtin_nontemporal_load(
            reinterpret_cast<const vint4*>(sh + 3 * e0 + 8));
        const float sf[12] = {
            (float)sA.x, (float)sA.y, (float)sA.z, (float)sA.w,
            (float)sB.x, (float)sB.y, (float)sB.z, (float)sB.w,
            (float)sC.x, (float)sC.y, (float)sC.z, (float)sC.w};

        int bv[4] = {0, 0, 0, 0};
        if (MULTI) {
            const vint4 b4 = __builtin_nontemporal_load(
                reinterpret_cast<const vint4*>(bmap + e0));
            bv[0] = b4.x; bv[1] = b4.y; bv[2] = b4.z; bv[3] = b4.w;
        }

        // 4) out_ei pass-through (NT, contiguous).
        __builtin_nontemporal_store(
            (vfloat4){(float)i4.x, (float)i4.y, (float)i4.z, (float)i4.w},
            reinterpret_cast<vfloat4*>(out_ei + e0));
        __builtin_nontemporal_store(
            (vfloat4){(float)j4.x, (float)j4.y, (float)j4.z, (float)j4.w},
            reinterpret_cast<vfloat4*>(out_ei + E + e0));

        // 5) Math.
        float w[4], v[12];
#pragma unroll
        for (int k = 0; k < 4; ++k) {
            float B00, B01, B02, B10, B11, B12, B20, B21, B22;
            if (MULTI) {
                const float* bb = box + 9LL * bv[k];
                B00 = bb[0]; B01 = bb[1]; B02 = bb[2];
                B10 = bb[3]; B11 = bb[4]; B12 = bb[5];
                B20 = bb[6]; B21 = bb[7]; B22 = bb[8];
            } else {
                B00 = b00; B01 = b01; B02 = b02;
                B10 = b10; B11 = b11; B12 = b12;
                B20 = b20; B21 = b21; B22 = b22;
            }
            const float sx = sf[3 * k + 0];
            const float sy = sf[3 * k + 1];
            const float sz = sf[3 * k + 2];
            // einsum 'en,enm->em': c[m] = sum_n s[n] * box[n][m]
            const float cx = sx * B00 + sy * B10 + sz * B20;
            const float cy = sx * B01 + sy * B11 + sz * B21;
            const float cz = sx * B02 + sy * B12 + sz * B22;

            const float dx = pjv[k].x - piv[k].x + cx;
            const float dy = pjv[k].y - piv[k].y + cy;
            const float dz = pjv[k].z - piv[k].z + cz;

            w[k] = sqrtf(dx * dx + dy * dy + dz * dz);
            v[3 * k + 0] = -dx;
            v[3 * k + 1] = -dy;
            v[3 * k + 2] = -dz;
        }

        // 6) out_w (NT, contiguous).
        __builtin_nontemporal_store(
            (vfloat4){w[0], w[1], w[2], w[3]},
            reinterpret_cast<vfloat4*>(out_w + e0));

        // 7) out_v via LDS transpose -> contiguous NT stores.
        {
            vfloat4* lrow = reinterpret_cast<vfloat4*>(&lds[tid * 12]);
            lrow[0] = (vfloat4){v[0], v[1], v[2], v[3]};
            lrow[1] = (vfloat4){v[4], v[5], v[6], v[7]};
            lrow[2] = (vfloat4){v[8], v[9], v[10], v[11]};
        }
        __syncthreads();
#pragma unroll
        for (int q = 0; q < 3; ++q) {
            const int idx = tid + BLOCK * q;          // float4 index in block
            const vfloat4 val =
                *reinterpret_cast<const vfloat4*>(&lds[idx * 4]);
            __builtin_nontemporal_store(
                val, reinterpret_cast<vfloat4*>(out_v + 3 * E0 + 4LL * idx));
        }
        __syncthreads();

        // 8) out_s via the same LDS buffer.
        {
            vfloat4* lrow = reinterpret_cast<vfloat4*>(&lds[tid * 12]);
            lrow[0] = (vfloat4){sf[0], sf[1], sf[2], sf[3]};
            lrow[1] = (vfloat4){sf[4], sf[5], sf[6], sf[7]};
            lrow[2] = (vfloat4){sf[8], sf[9], sf[10], sf[11]};
        }
        __syncthreads();
#pragma unroll
        for (int q = 0; q < 3; ++q) {
            const int idx = tid + BLOCK * q;
            const vfloat4 val =
                *reinterpret_cast<const vfloat4*>(&lds[idx * 4]);
            __builtin_nontemporal_store(
                val, reinterpret_cast<vfloat4*>(out_s + 3 * E0 + 4LL * idx));
        }
    } else {
        // ---------- partial tail block: scalar per-edge ----------
        for (long long e = E0 + tid; e < E; e += BLOCK) {
            const int i = ei[e];
            const int j = ei[E + e];
            const int s0 = sh[3 * e], s1 = sh[3 * e + 1], s2 = sh[3 * e + 2];
            out_ei[e]     = (float)i;
            out_ei[E + e] = (float)j;
            out_s[3 * e]     = (float)s0;
            out_s[3 * e + 1] = (float)s1;
            out_s[3 * e + 2] = (float)s2;

            float B00, B01, B02, B10, B11, B12, B20, B21, B22;
            if (MULTI) {
                const float* bb = box + 9LL * bmap[e];
                B00 = bb[0]; B01 = bb[1]; B02 = bb[2];
                B10 = bb[3]; B11 = bb[4]; B12 = bb[5];
                B20 = bb[6]; B21 = bb[7]; B22 = bb[8];
            } else {
                B00 = b00; B01 = b01; B02 = b02;
                B10 = b10; B11 = b11; B12 = b12;
                B20 = b20; B21 = b21; B22 = b22;
            }
            const float sx = (float)s0, sy = (float)s1, sz = (float)s2;
            const float cx = sx * B00 + sy * B10 + sz * B20;
            const float cy = sx * B01 + sy * B11 + sz * B21;
            const float cz = sx * B02 + sy * B12 + sz * B22;
            const float dx = pos[3LL * j + 0] - pos[3LL * i + 0] + cx;
            const float dy = pos[3LL * j + 1] - pos[3LL * i + 1] + cy;
            const float dz = pos[3LL * j + 2] - pos[3LL * i + 2] + cz;
            out_w[e] = sqrtf(dx * dx + dy * dy + dz * dz);
            out_v[3 * e + 0] = -dx;
            out_v[3 * e + 1] = -dy;
            out_v[3 * e + 2] = -dz;
        }
    }
}

extern "C" void kernel_launch(void* const* d_in, const int* in_sizes, int n_in,
                              void* d_out, int out_size, void* d_ws, size_t ws_size,
                              hipStream_t stream) {
    const float* pos  = (const float*)d_in[0];
    const float* box  = (const float*)d_in[1];
    const int*   ei   = (const int*)d_in[2];
    const int*   sh   = (const int*)d_in[3];
    const int*   bmap = (const int*)d_in[4];
    float* out = (float*)d_out;

    const long long E = (long long)in_sizes[4];     // batch_map length
    const int n_struct = in_sizes[1] / 9;

    long long blocks = (E + EPB - 1) / EPB;         // 6250 for E = 6.4M
    if (blocks < 1) blocks = 1;

    if (n_struct == 1) {
        pd_kernel<false><<<(int)blocks, BLOCK, 0, stream>>>(
            pos, box, ei, sh, bmap, out, E);
    } else {
        pd_kernel<true><<<(int)blocks, BLOCK, 0, stream>>>(
            pos, box, ei, sh, bmap, out, E);
    }
}